// Round 17
// baseline (322.196 us; speedup 1.0000x reference)
//
#include <hip/hip_runtime.h>
#include <math.h>

#define NPTS 4096
#define KNN  20
#define NOUT 64
#define WPB  2               // waves per block (barrier-free; packaging only)
#define QPW  4               // queries per wave
#define QBLK (WPB * QPW)     // 8 queries per block
#define BLKT (WPB * 64)      // 128 threads
#define PCAP 128             // per-query pool capacity == selection capacity

// monotone float->uint map (total order preserved)
__device__ __forceinline__ unsigned ord32(float f) {
    unsigned u = __float_as_uint(f);
    int m = ((int)u) >> 31;
    return u ^ ((unsigned)m | 0x80000000u);
}
// inverse of ord32
__device__ __forceinline__ float iord32(unsigned r) {
    unsigned u = (r & 0x80000000u) ? (r ^ 0x80000000u) : ~r;
    return __uint_as_float(u);
}
__device__ __forceinline__ int mbcnt64(unsigned long long m) {
    return __builtin_amdgcn_mbcnt_hi((unsigned)(m >> 32),
           __builtin_amdgcn_mbcnt_lo((unsigned)m, 0));
}

// prologue: xq[b][j] = (x0, x1, x2, -(x0^2+x1^2+x2^2))
__global__ __launch_bounds__(256) void pack_kernel(const float* __restrict__ x,
                                                   float4* __restrict__ xq) {
    const int i = blockIdx.x * 256 + threadIdx.x;   // over B*NPTS
    const int b = i >> 12, j = i & (NPTS - 1);
    const float* xb = x + (size_t)b * 3 * NPTS;
    const float a0 = xb[j], a1 = xb[NPTS + j], a2 = xb[2 * NPTS + j];
    xq[i] = make_float4(a0, a1, a2, -fmaf(a0, a0, fmaf(a1, a1, a2 * a2)));
}

__global__ __launch_bounds__(BLKT, 8) void edgeconv_kernel(
    const float4* __restrict__ xq,    // (B, N) packed points
    const float* __restrict__ Wm,     // (64, 6)
    const float* __restrict__ gamma,
    const float* __restrict__ beta,
    const float* __restrict__ mean,
    const float* __restrict__ var,
    float* __restrict__ out)          // (B, 64, N)
{
    const int bid = blockIdx.x;
    const int b   = bid >> 9;                    // 512 blocks per batch
    const int n0  = (bid & 511) * QBLK;
    const int t    = threadIdx.x;
    const int lane = t & 63;
    const int w    = t >> 6;

    __shared__ unsigned long long pool[QBLK * PCAP];    // 8 KB, wave-private rows

    const float4* xqb = xq + (size_t)b * NPTS;

    // ---- query constants (uniform -> scalar loads) ----
    const int na = __builtin_amdgcn_readfirstlane(n0 + QPW * w);
    float q0[QPW], q1[QPW], q2[QPW];
    #pragma unroll
    for (int q = 0; q < QPW; ++q) {
        const float4 pv = xqb[na + q];
        q0[q] = 2.f * pv.x; q1[q] = 2.f * pv.y; q2[q] = 2.f * pv.z;
    }

    // ---- max pass: ALL 4096 candidates, 2 lane-maxima groups per query ----
    float vm0[QPW], vm1[QPW];
    #pragma unroll
    for (int q = 0; q < QPW; ++q) { vm0[q] = -INFINITY; vm1[q] = -INFINITY; }
    #pragma unroll
    for (int g = 0; g < NPTS / 256; ++g) {              // 16 iters of 4 loads
        float4 cc[4];
        #pragma unroll
        for (int u = 0; u < 4; ++u) cc[u] = xqb[(g * 4 + u) * 64 + lane];
        #pragma unroll
        for (int u = 0; u < 4; ++u) {
            #pragma unroll
            for (int q = 0; q < QPW; ++q) {
                const float e = fmaf(q0[q], cc[u].x, fmaf(q1[q], cc[u].y, fmaf(q2[q], cc[u].z, cc[u].w)));
                if (g < 8) vm0[q] = fmaxf(vm0[q], e);
                else       vm1[q] = fmaxf(vm1[q], e);
            }
        }
    }

    // ---- T[q] ~ 20th-largest of 128 group maxima (16-bit ballot bsearch) ----
    // 20 distinct candidates >= T => true 20th-best >= T => superset safe.
    // 16-bit truncation only lowers T (still safe, slightly larger pool).
    float Tf[QPW];
    #pragma unroll
    for (int q = 0; q < QPW; ++q) {
        const unsigned h0 = ord32(vm0[q]) >> 16;
        const unsigned h1 = ord32(vm1[q]) >> 16;
        unsigned K = 0;
        #pragma unroll
        for (int bit = 15; bit >= 0; --bit) {
            const unsigned p = K | (1u << bit);
            const int c = __popcll(__ballot(h0 >= p)) + __popcll(__ballot(h1 >= p));
            if (c >= KNN) K = p;
        }
        Tf[q] = iord32(K << 16);
    }

    const int invl = (NPTS - 1) - lane;

    // ---- filter pass: ballot-ranked append (no atomics; deterministic) ----
    int base0 = 0, base1 = 0, base2_ = 0, base3 = 0;
    #pragma unroll
    for (int g = 0; g < NPTS / 256; ++g) {              // 16 iters of 4 loads
        float4 cc[4];
        #pragma unroll
        for (int u = 0; u < 4; ++u) cc[u] = xqb[(g * 4 + u) * 64 + lane];
        #pragma unroll
        for (int u = 0; u < 4; ++u) {
            const unsigned tag = (unsigned)(invl - (g * 4 + u) * 64);
            const float e0 = fmaf(q0[0], cc[u].x, fmaf(q1[0], cc[u].y, fmaf(q2[0], cc[u].z, cc[u].w)));
            const float e1 = fmaf(q0[1], cc[u].x, fmaf(q1[1], cc[u].y, fmaf(q2[1], cc[u].z, cc[u].w)));
            const float e2 = fmaf(q0[2], cc[u].x, fmaf(q1[2], cc[u].y, fmaf(q2[2], cc[u].z, cc[u].w)));
            const float e3 = fmaf(q0[3], cc[u].x, fmaf(q1[3], cc[u].y, fmaf(q2[3], cc[u].z, cc[u].w)));
            const bool s0 = e0 >= Tf[0], s1 = e1 >= Tf[1];
            const bool s2 = e2 >= Tf[2], s3 = e3 >= Tf[3];
            if (__ballot(s0 | s1 | s2 | s3)) {          // any4 gate (one branch)
                const unsigned long long m0 = __ballot(s0);
                const unsigned long long m1 = __ballot(s1);
                const unsigned long long m2 = __ballot(s2);
                const unsigned long long m3 = __ballot(s3);
                if (s0) {
                    const int pos = base0 + mbcnt64(m0);
                    if (pos < PCAP)
                        pool[(QPW * w + 0) * PCAP + pos] =
                            ((unsigned long long)ord32(e0) << 32) | tag;
                }
                if (s1) {
                    const int pos = base1 + mbcnt64(m1);
                    if (pos < PCAP)
                        pool[(QPW * w + 1) * PCAP + pos] =
                            ((unsigned long long)ord32(e1) << 32) | tag;
                }
                if (s2) {
                    const int pos = base2_ + mbcnt64(m2);
                    if (pos < PCAP)
                        pool[(QPW * w + 2) * PCAP + pos] =
                            ((unsigned long long)ord32(e2) << 32) | tag;
                }
                if (s3) {
                    const int pos = base3 + mbcnt64(m3);
                    if (pos < PCAP)
                        pool[(QPW * w + 3) * PCAP + pos] =
                            ((unsigned long long)ord32(e3) << 32) | tag;
                }
                base0 += __popcll(m0);
                base1 += __popcll(m1);
                base2_ += __popcll(m2);
                base3 += __popcll(m3);
            }
        }
    }
    const int bases[QPW] = {base0, base1, base2_, base3};

    // ---- exact top-20 set per query: 32-bit ballot bsearch, 2 entries/lane ----
    // Wave-private pool; same-wave DS is in-order -> no barrier needed.
    unsigned myidx[QPW];
    #pragma unroll
    for (int q = 0; q < QPW; ++q) {
        const int pr = QPW * w + q;
        unsigned long long* pl = pool + (size_t)pr * PCAP;
        int cw = bases[q];                             // wave-uniform scalar
        if (cw > PCAP) cw = PCAP;                      // >= 20 guaranteed

        // sentinel 0: ord32(finite) >= 1, so pad entries never counted
        const unsigned long long e0 = (lane < cw) ? pl[lane] : 0ull;
        const unsigned long long e1 = (lane + 64 < cw) ? pl[lane + 64] : 0ull;
        const unsigned k0 = (unsigned)(e0 >> 32), t0 = (unsigned)e0;
        const unsigned k1 = (unsigned)(e1 >> 32), t1 = (unsigned)e1;

        unsigned K = 0;
        #pragma unroll
        for (int bit = 31; bit >= 0; --bit) {
            const unsigned p = K | (1u << bit);
            const int c = __popcll(__ballot(k0 >= p)) + __popcll(__ballot(k1 >= p));
            if (c >= KNN) K = p;
        }

        unsigned long long g0 = __ballot(k0 > K);
        unsigned long long g1 = __ballot(k1 > K);
        const int m = __popcll(g0) + __popcll(g1);     // <= 19
        unsigned long long s0 = __ballot(k0 == K);
        unsigned long long s1 = __ballot(k1 == K);
        const int r = KNN - m;                         // >= 1 ties needed
        if (__popcll(s0) + __popcll(s1) > r) {
            // tie split: choose r ties with largest tag (= lowest index)
            unsigned TT = 0;
            #pragma unroll
            for (int bit = 11; bit >= 0; --bit) {      // tags < 4096
                const unsigned p = TT | (1u << bit);
                const int c = __popcll(__ballot(k0 == K && t0 >= p)) +
                              __popcll(__ballot(k1 == K && t1 >= p));
                if (c >= r) TT = p;
            }
            s0 = __ballot(k0 == K && t0 >= TT);
            s1 = __ballot(k1 == K && t1 >= TT);
        }

        unsigned* idxq = (unsigned*)pl;                // alias own (consumed) pool
        if ((g0 >> lane) & 1) idxq[mbcnt64(g0)] = t0;
        if ((g1 >> lane) & 1) idxq[__popcll(g0) + mbcnt64(g1)] = t1;
        if ((s0 >> lane) & 1) idxq[m + mbcnt64(s0)] = t0;
        if ((s1 >> lane) & 1) idxq[m + __popcll(s0) + mbcnt64(s1)] = t1;
        myidx[q] = idxq[(lane < KNN) ? lane : 0];
    }

    // ---- epilogue: lane = output channel; neighbors via scalar loads ----
    const int o = lane;
    const float iv   = gamma[o] / sqrtf(var[o] + 1e-5f);
    const float bias = beta[o] - mean[o] * iv;
    const float* Wr = Wm + o * 6;
    const float w0p = Wr[0] * iv, w1p = Wr[1] * iv, w2p = Wr[2] * iv;
    const float w3p = Wr[3] * iv, w4p = Wr[4] * iv, w5p = Wr[5] * iv;

    float bests[QPW];
    #pragma unroll
    for (int q = 0; q < QPW; ++q) {
        const float4 pv = xqb[na + q];                 // scalar reload
        const float basep = fmaf(w3p, pv.x, fmaf(w4p, pv.y, fmaf(w5p, pv.z, bias)));
        const float base2 = basep - fmaf(w0p, pv.x, fmaf(w1p, pv.y, w2p * pv.z));
        float best = -INFINITY;
        #pragma unroll
        for (int k = 0; k < KNN; ++k) {
            const int lk = __builtin_amdgcn_readlane((int)myidx[q], k);
            const int gi = __builtin_amdgcn_readfirstlane((NPTS - 1) - lk);
            const float4 f = xqb[gi];                  // s_load_dwordx4
            float y = fmaf(w0p, f.x, fmaf(w1p, f.y, fmaf(w2p, f.z, base2)));
            y = fmaxf(y, 0.2f * y);                    // LeakyReLU
            best = fmaxf(best, y);
        }
        bests[q] = best;
    }

    // ---- direct store: lane o writes its 4 consecutive n's as one float4 ----
    float4 res;
    res.x = bests[0]; res.y = bests[1]; res.z = bests[2]; res.w = bests[3];
    *(float4*)(out + ((size_t)b * NOUT + o) * NPTS + na) = res;
}

extern "C" void kernel_launch(void* const* d_in, const int* in_sizes, int n_in,
                              void* d_out, int out_size, void* d_ws, size_t ws_size,
                              hipStream_t stream) {
    const float* x     = (const float*)d_in[0];
    const float* Wm    = (const float*)d_in[1];
    const float* gamma = (const float*)d_in[2];
    const float* beta  = (const float*)d_in[3];
    const float* mean  = (const float*)d_in[4];
    const float* var   = (const float*)d_in[5];
    float* out = (float*)d_out;
    float4* xq = (float4*)d_ws;                    // B*NPTS float4 = 512 KB

    const int B = in_sizes[0] / (3 * NPTS);        // 8
    pack_kernel<<<B * NPTS / 256, 256, 0, stream>>>(x, xq);
    const int nblocks = B * (NPTS / QBLK);         // 8 * 512 = 4096
    edgeconv_kernel<<<nblocks, BLKT, 0, stream>>>(xq, Wm, gamma, beta, mean, var, out);
}

// Round 18
// 126.374 us; speedup vs baseline: 2.5495x; 2.5495x over previous
//
#include <hip/hip_runtime.h>
#include <math.h>

#define NPTS 4096
#define KNN  20
#define NOUT 64
#define WPB  2               // waves per block (barrier-free; packaging only)
#define QPW  4               // queries per wave
#define QBLK (WPB * QPW)     // 8 queries per block
#define BLKT (WPB * 64)      // 128 threads
#define PCAP 128             // per-query pool capacity == selection capacity
#define MITER 8              // max-pass iterations (2048-candidate sample)

// monotone float->uint map (total order preserved)
__device__ __forceinline__ unsigned ord32(float f) {
    unsigned u = __float_as_uint(f);
    int m = ((int)u) >> 31;
    return u ^ ((unsigned)m | 0x80000000u);
}
// inverse of ord32
__device__ __forceinline__ float iord32(unsigned r) {
    unsigned u = (r & 0x80000000u) ? (r ^ 0x80000000u) : ~r;
    return __uint_as_float(u);
}
__device__ __forceinline__ int mbcnt64(unsigned long long m) {
    return __builtin_amdgcn_mbcnt_hi((unsigned)(m >> 32),
           __builtin_amdgcn_mbcnt_lo((unsigned)m, 0));
}

// prologue: xq[b][j] = (x0, x1, x2, -(x0^2+x1^2+x2^2))
__global__ __launch_bounds__(256) void pack_kernel(const float* __restrict__ x,
                                                   float4* __restrict__ xq) {
    const int i = blockIdx.x * 256 + threadIdx.x;   // over B*NPTS
    const int b = i >> 12, j = i & (NPTS - 1);
    const float* xb = x + (size_t)b * 3 * NPTS;
    const float a0 = xb[j], a1 = xb[NPTS + j], a2 = xb[2 * NPTS + j];
    xq[i] = make_float4(a0, a1, a2, -fmaf(a0, a0, fmaf(a1, a1, a2 * a2)));
}

__global__ __launch_bounds__(BLKT, 8) void edgeconv_kernel(
    const float4* __restrict__ xq,    // (B, N) packed points
    const float* __restrict__ Wm,     // (64, 6)
    const float* __restrict__ gamma,
    const float* __restrict__ beta,
    const float* __restrict__ mean,
    const float* __restrict__ var,
    float* __restrict__ out)          // (B, 64, N)
{
    const int bid = blockIdx.x;
    const int b   = bid >> 9;                    // 512 blocks per batch
    const int n0  = (bid & 511) * QBLK;
    const int t    = threadIdx.x;
    const int lane = t & 63;
    const int w    = t >> 6;

    __shared__ unsigned long long pool[QBLK * PCAP];    // 8 KB, wave-private rows
    __shared__ int cnt[QBLK];

    const float4* xqb = xq + (size_t)b * NPTS;

    // own wave's counters only; same-wave DS ops are in-order -> no barrier
    if (lane < QPW) cnt[QPW * w + lane] = 0;

    // ---- query constants (uniform -> scalar loads) ----
    const int na = __builtin_amdgcn_readfirstlane(n0 + QPW * w);
    float q0[QPW], q1[QPW], q2[QPW];
    #pragma unroll
    for (int q = 0; q < QPW; ++q) {
        const float4 pv = xqb[na + q];
        q0[q] = 2.f * pv.x; q1[q] = 2.f * pv.y; q2[q] = 2.f * pv.z;
    }

    // ---- max pass: 2048-candidate sample, 2 lane-maxima groups per query ----
    float vm0[QPW], vm1[QPW];
    #pragma unroll
    for (int q = 0; q < QPW; ++q) { vm0[q] = -INFINITY; vm1[q] = -INFINITY; }
    #pragma unroll
    for (int g = 0; g < MITER; ++g) {                   // 8 iters of 4 loads
        float4 cc[4];
        #pragma unroll
        for (int u = 0; u < 4; ++u) cc[u] = xqb[(g * 4 + u) * 64 + lane];
        #pragma unroll
        for (int u = 0; u < 4; ++u) {
            #pragma unroll
            for (int q = 0; q < QPW; ++q) {
                const float e = fmaf(q0[q], cc[u].x, fmaf(q1[q], cc[u].y, fmaf(q2[q], cc[u].z, cc[u].w)));
                if (g < MITER / 2) vm0[q] = fmaxf(vm0[q], e);
                else               vm1[q] = fmaxf(vm1[q], e);
            }
        }
    }

    // ---- T[q] ~ 20th-largest of 128 group maxima (16-bit ballot bsearch) ----
    // The 20 top group-maxima are 20 distinct candidates >= T, so the true
    // 20th-best >= T => {all candidates >= T} is a superset of the exact
    // top-20. 16-bit truncation only lowers T (safe, slightly larger pool).
    float Tf[QPW];
    #pragma unroll
    for (int q = 0; q < QPW; ++q) {
        const unsigned h0 = ord32(vm0[q]) >> 16;
        const unsigned h1 = ord32(vm1[q]) >> 16;
        unsigned K = 0;
        #pragma unroll
        for (int bit = 15; bit >= 0; --bit) {
            const unsigned p = K | (1u << bit);
            const int c = __popcll(__ballot(h0 >= p)) + __popcll(__ballot(h1 >= p));
            if (c >= KNN) K = p;
        }
        Tf[q] = iord32(K << 16);
    }

    const int invl = (NPTS - 1) - lane;

    // ---- filter pass: all 4096 candidates, fused filter+append ----
    #pragma unroll
    for (int g = 0; g < NPTS / 256; ++g) {              // 16 iters of 4 loads
        float4 cc[4];
        #pragma unroll
        for (int u = 0; u < 4; ++u) cc[u] = xqb[(g * 4 + u) * 64 + lane];
        #pragma unroll
        for (int u = 0; u < 4; ++u) {
            const unsigned tag = (unsigned)(invl - (g * 4 + u) * 64);
            #pragma unroll
            for (int q = 0; q < QPW; ++q) {
                const float e = fmaf(q0[q], cc[u].x, fmaf(q1[q], cc[u].y, fmaf(q2[q], cc[u].z, cc[u].w)));
                if (e >= Tf[q]) {
                    const int pos = atomicAdd(&cnt[QPW * w + q], 1);
                    if (pos < PCAP)
                        pool[(QPW * w + q) * PCAP + pos] =
                            ((unsigned long long)ord32(e) << 32) | tag;
                }
            }
        }
    }

    // ---- exact top-20 set per query: 32-bit ballot bsearch, 2 entries/lane ----
    // Wave-private pool; same-wave DS is in-order -> no barrier needed.
    unsigned myidx[QPW];
    #pragma unroll
    for (int q = 0; q < QPW; ++q) {
        const int pr = QPW * w + q;
        unsigned long long* pl = pool + (size_t)pr * PCAP;
        int cw = __builtin_amdgcn_readfirstlane(cnt[pr]);
        if (cw > PCAP) cw = PCAP;                      // >= 20 guaranteed

        // sentinel 0: ord32(finite) >= 1, so pad entries never counted
        const unsigned long long e0 = (lane < cw) ? pl[lane] : 0ull;
        const unsigned long long e1 = (lane + 64 < cw) ? pl[lane + 64] : 0ull;
        const unsigned k0 = (unsigned)(e0 >> 32), t0 = (unsigned)e0;
        const unsigned k1 = (unsigned)(e1 >> 32), t1 = (unsigned)e1;

        unsigned K = 0;
        #pragma unroll
        for (int bit = 31; bit >= 0; --bit) {
            const unsigned p = K | (1u << bit);
            const int c = __popcll(__ballot(k0 >= p)) + __popcll(__ballot(k1 >= p));
            if (c >= KNN) K = p;
        }

        unsigned long long g0 = __ballot(k0 > K);
        unsigned long long g1 = __ballot(k1 > K);
        const int m = __popcll(g0) + __popcll(g1);     // <= 19
        unsigned long long s0 = __ballot(k0 == K);
        unsigned long long s1 = __ballot(k1 == K);
        const int r = KNN - m;                         // >= 1 ties needed
        if (__popcll(s0) + __popcll(s1) > r) {
            // tie split: choose r ties with largest tag (= lowest index)
            unsigned TT = 0;
            #pragma unroll
            for (int bit = 11; bit >= 0; --bit) {      // tags < 4096
                const unsigned p = TT | (1u << bit);
                const int c = __popcll(__ballot(k0 == K && t0 >= p)) +
                              __popcll(__ballot(k1 == K && t1 >= p));
                if (c >= r) TT = p;
            }
            s0 = __ballot(k0 == K && t0 >= TT);
            s1 = __ballot(k1 == K && t1 >= TT);
        }

        unsigned* idxq = (unsigned*)pl;                // alias own (consumed) pool
        if ((g0 >> lane) & 1) idxq[mbcnt64(g0)] = t0;
        if ((g1 >> lane) & 1) idxq[__popcll(g0) + mbcnt64(g1)] = t1;
        if ((s0 >> lane) & 1) idxq[m + mbcnt64(s0)] = t0;
        if ((s1 >> lane) & 1) idxq[m + __popcll(s0) + mbcnt64(s1)] = t1;
        myidx[q] = idxq[(lane < KNN) ? lane : 0];
    }

    // ---- epilogue: lane = output channel; neighbors via scalar loads ----
    const int o = lane;
    const float iv   = gamma[o] / sqrtf(var[o] + 1e-5f);
    const float bias = beta[o] - mean[o] * iv;
    const float* Wr = Wm + o * 6;
    const float w0p = Wr[0] * iv, w1p = Wr[1] * iv, w2p = Wr[2] * iv;
    const float w3p = Wr[3] * iv, w4p = Wr[4] * iv, w5p = Wr[5] * iv;

    float bests[QPW];
    #pragma unroll
    for (int q = 0; q < QPW; ++q) {
        const float4 pv = xqb[na + q];                 // scalar reload
        const float basep = fmaf(w3p, pv.x, fmaf(w4p, pv.y, fmaf(w5p, pv.z, bias)));
        const float base2 = basep - fmaf(w0p, pv.x, fmaf(w1p, pv.y, w2p * pv.z));
        float best = -INFINITY;
        #pragma unroll
        for (int k = 0; k < KNN; ++k) {
            const int lk = __builtin_amdgcn_readlane((int)myidx[q], k);
            const int gi = __builtin_amdgcn_readfirstlane((NPTS - 1) - lk);
            const float4 f = xqb[gi];                  // s_load_dwordx4
            float y = fmaf(w0p, f.x, fmaf(w1p, f.y, fmaf(w2p, f.z, base2)));
            y = fmaxf(y, 0.2f * y);                    // LeakyReLU
            best = fmaxf(best, y);
        }
        bests[q] = best;
    }

    // ---- direct store: lane o writes its 4 consecutive n's as one float4 ----
    float4 res;
    res.x = bests[0]; res.y = bests[1]; res.z = bests[2]; res.w = bests[3];
    *(float4*)(out + ((size_t)b * NOUT + o) * NPTS + na) = res;
}

extern "C" void kernel_launch(void* const* d_in, const int* in_sizes, int n_in,
                              void* d_out, int out_size, void* d_ws, size_t ws_size,
                              hipStream_t stream) {
    const float* x     = (const float*)d_in[0];
    const float* Wm    = (const float*)d_in[1];
    const float* gamma = (const float*)d_in[2];
    const float* beta  = (const float*)d_in[3];
    const float* mean  = (const float*)d_in[4];
    const float* var   = (const float*)d_in[5];
    float* out = (float*)d_out;
    float4* xq = (float4*)d_ws;                    // B*NPTS float4 = 512 KB

    const int B = in_sizes[0] / (3 * NPTS);        // 8
    pack_kernel<<<B * NPTS / 256, 256, 0, stream>>>(x, xq);
    const int nblocks = B * (NPTS / QBLK);         // 8 * 512 = 4096
    edgeconv_kernel<<<nblocks, BLKT, 0, stream>>>(xq, Wm, gamma, beta, mean, var, out);
}